// Round 3
// baseline (129.865 us; speedup 1.0000x reference)
//
#include <hip/hip_runtime.h>
#include <stdint.h>

// fp32 inputs, fp32 outputs:
// qps/kps: [256][32][8][64] f32 ; qpn/kpn: [256][8][8][64] f32
// d_out: f32, FIRST s_ps repeat-expanded [8][8][256][256], THEN s_pn tiled.
//
// R17: MEASUREMENT ROUND. Kernels byte-identical to R16. Both kernels are
// idempotent, so each is launched TWICE:
//   dur_probe = OH + 2S + 2W ; dur_base(108.6) = OH + S + W
//   => OH = 2*108.6 - dur_probe ; S+W = dur_probe - 108.6
// This splits harness fixed overhead (re-poison fills ~41.5us etc.) from
// controllable kernel time, after two structural rounds moved nothing.

__global__ __launch_bounds__(256, 2)
void scores_kernel(const float* __restrict__ qps,
                   const float* __restrict__ kps,
                   const float* __restrict__ qpn,
                   const float* __restrict__ kpn,
                   float* __restrict__ ws_ps,   // [64][8][1024] chunk partials
                   float* __restrict__ ws_pn)   // [64][8][64]   chunk partials
{
    // per-channel tiles: [ch][0]=Q, [ch][1]=K; 32 rows x 17 float4 (pad)
    __shared__ float4 T[4][2][32 * 17];        // 69,632 B -> 2 blocks/CU
    const int tid  = threadIdx.x;
    const int wv   = tid >> 6;
    const int lane = tid & 63;
    const int blk  = blockIdx.x;

    if (blk < 512) {
        // ---- patch_size: block = (a, chunk); wave wv = channel chunk*4+wv ----
        const int a     = blk >> 3;    // bo*8 + h
        const int chunk = blk & 7;
        const int bo = a >> 3, h = a & 7;
        const int b  = bo * 32 + chunk * 4 + wv;    // this wave's channel

        const float4* Q4 = reinterpret_cast<const float4*>(qps);
        const float4* K4 = reinterpret_cast<const float4*>(kps);

        // ---- stage this wave's channel (16 KB): 16-lane groups read 256 B
        // contiguous row segments; LDS rows padded to 17 f4 ----
        const int sr = lane >> 4;      // 0..3
        const int f  = lane & 15;      // 0..15
        float4 qreg[8], kreg[8];
        #pragma unroll
        for (int i = 0; i < 8; ++i) {
            const int row = i * 4 + sr;
            qreg[i] = Q4[((b * 32 + row) * 8 + h) * 16 + f];
            kreg[i] = K4[((b * 32 + row) * 8 + h) * 16 + f];
        }
        #pragma unroll
        for (int i = 0; i < 8; ++i) {
            const int row = i * 4 + sr;
            T[wv][0][row * 17 + f] = qreg[i];
            T[wv][1][row * 17 + f] = kreg[i];
        }
        // NO __syncthreads: wave-lockstep LDS visibility (own writes only).

        // ---- compute: lane = (rg, cg); rows rg+8r, cols cg+8u (r,u=0..3) ----
        const int rg = lane >> 3;
        const int cg = lane & 7;

        float acc[4][4];
        #pragma unroll
        for (int r = 0; r < 4; ++r)
            #pragma unroll
            for (int u = 0; u < 4; ++u) acc[r][u] = 0.f;

        #pragma unroll
        for (int c = 0; c < 16; ++c) {
            float4 qv[4], kv[4];
            #pragma unroll
            for (int r = 0; r < 4; ++r) qv[r] = T[wv][0][(rg + 8 * r) * 17 + c];
            #pragma unroll
            for (int u = 0; u < 4; ++u) kv[u] = T[wv][1][(cg + 8 * u) * 17 + c];
            #pragma unroll
            for (int r = 0; r < 4; ++r)
                #pragma unroll
                for (int u = 0; u < 4; ++u) {
                    acc[r][u] = fmaf(qv[r].x, kv[u].x, acc[r][u]);
                    acc[r][u] = fmaf(qv[r].y, kv[u].y, acc[r][u]);
                    acc[r][u] = fmaf(qv[r].z, kv[u].z, acc[r][u]);
                    acc[r][u] = fmaf(qv[r].w, kv[u].w, acc[r][u]);
                }
        }

        // ---- softmax per row; /32 for channel mean ----
        #pragma unroll
        for (int r = 0; r < 4; ++r) {
            float v0 = acc[r][0] * 0.125f, v1 = acc[r][1] * 0.125f;
            float v2 = acc[r][2] * 0.125f, v3 = acc[r][3] * 0.125f;
            float m = fmaxf(fmaxf(v0, v1), fmaxf(v2, v3));
            m = fmaxf(m, __shfl_xor(m, 1));
            m = fmaxf(m, __shfl_xor(m, 2));
            m = fmaxf(m, __shfl_xor(m, 4));
            float e0 = __expf(v0 - m), e1 = __expf(v1 - m);
            float e2 = __expf(v2 - m), e3 = __expf(v3 - m);
            float s = (e0 + e1) + (e2 + e3);
            s += __shfl_xor(s, 1);
            s += __shfl_xor(s, 2);
            s += __shfl_xor(s, 4);
            const float inv = 1.f / (s * 32.f);
            acc[r][0] = e0 * inv; acc[r][1] = e1 * inv;
            acc[r][2] = e2 * inv; acc[r][3] = e3 * inv;
        }

        // ---- cross-wave (4-channel) sum via swizzled LDS ----
        __syncthreads();                 // everyone done with tiles
        float* P = reinterpret_cast<float*>(T);   // [4][1024] floats
        #pragma unroll
        for (int r = 0; r < 4; ++r) {
            const int row = rg + 8 * r;
            const int sw  = (row & 3) << 3;
            #pragma unroll
            for (int u = 0; u < 4; ++u) {
                const int col = cg + 8 * u;
                P[wv * 1024 + row * 32 + (col ^ sw)] = acc[r][u];
            }
        }
        __syncthreads();

        // reduce channels in order wv=0..3; store coalesced f4
        {
            const int row = tid >> 3;
            const int c0  = (tid & 7) * 4;
            const int sw  = (row & 3) << 3;
            float vx[4];
            #pragma unroll
            for (int x = 0; x < 4; ++x) {
                const int ci = row * 32 + ((c0 + x) ^ sw);
                float v = P[ci];
                v += P[1024 + ci];
                v += P[2048 + ci];
                v += P[3072 + ci];
                vx[x] = v;
            }
            float4 o; o.x = vx[0]; o.y = vx[1]; o.z = vx[2]; o.w = vx[3];
            reinterpret_cast<float4*>(ws_ps + (a * 8 + chunk) * 1024)[tid] = o;
        }
    } else {
        // ---- patch_num: block (a2, chunk); wave wv = channel chunk*4+wv ----
        float* red = reinterpret_cast<float*>(T);   // [4][64] reuse
        const int bb    = blk - 512;
        const int a2    = bb >> 3;     // bo*8 + h
        const int chunk = bb & 7;
        const int bo = a2 >> 3, h = a2 & 7;
        const int b  = bo * 32 + chunk * 4 + wv;
        const int i = lane >> 3, j = lane & 7;
        const float4* qv = reinterpret_cast<const float4*>(qpn) + ((b * 8 + i) * 8 + h) * 16;
        const float4* kv = reinterpret_cast<const float4*>(kpn) + ((b * 8 + j) * 8 + h) * 16;

        float acc = 0.f;
        #pragma unroll
        for (int c = 0; c < 16; ++c) {
            float4 q = qv[c], k = kv[c];
            acc = fmaf(q.x, k.x, acc);
            acc = fmaf(q.y, k.y, acc);
            acc = fmaf(q.z, k.z, acc);
            acc = fmaf(q.w, k.w, acc);
        }
        const float s = acc * 0.125f;
        float m = s;
        m = fmaxf(m, __shfl_xor(m, 1));
        m = fmaxf(m, __shfl_xor(m, 2));
        m = fmaxf(m, __shfl_xor(m, 4));
        float e = __expf(s - m);
        float sum = e;
        sum += __shfl_xor(sum, 1);
        sum += __shfl_xor(sum, 2);
        sum += __shfl_xor(sum, 4);

        red[wv * 64 + lane] = e / (sum * 32.f);
        __syncthreads();
        if (tid < 64) {
            ws_pn[(a2 * 8 + chunk) * 64 + tid] =
                (red[0 * 64 + tid] + red[1 * 64 + tid]) +
                (red[2 * 64 + tid] + red[3 * 64 + tid]);
        }
    }
}

// Fused 8-chunk reduce + expansion writer.
__global__ __launch_bounds__(256)
void writer_kernel(const float* __restrict__ ws_ps,
                   const float* __restrict__ ws_pn,
                   float* __restrict__ out)
{
    const int g = blockIdx.x * 256 + threadIdx.x;   // float4 index
    float4* o4 = reinterpret_cast<float4*>(out);
    if (g < 1048576) {
        // out0[a][i][j] = sum_c ws_ps[a][c][(i>>3)*32 + (j>>3)]
        const int a  = g >> 14;
        const int r  = g & 16383;
        const int i  = r >> 6;
        const int j4 = r & 63;
        const float* base = ws_ps + a * 8192 + (i >> 3) * 32 + (j4 >> 1);
        float v = 0.f;
        #pragma unroll
        for (int c = 0; c < 8; ++c) v += base[c * 1024];   // chunk-sequential
        float4 o; o.x = v; o.y = v; o.z = v; o.w = v;
        o4[g] = o;
    } else {
        // out1[a][i][j] = sum_c ws_pn[a][c][(i&7)*8 + (j&7)]
        const int g2 = g - 1048576;
        const int a  = g2 >> 14;
        const int r  = g2 & 16383;
        const int i  = r >> 6;
        const int j4 = r & 63;
        const float4* base = reinterpret_cast<const float4*>(
            ws_pn + a * 512 + (i & 7) * 8 + 4 * (j4 & 1));
        float4 v; v.x = 0.f; v.y = 0.f; v.z = 0.f; v.w = 0.f;
        #pragma unroll
        for (int c = 0; c < 8; ++c) {
            float4 t = base[c * 16];                       // chunk-sequential
            v.x += t.x; v.y += t.y; v.z += t.z; v.w += t.w;
        }
        o4[g] = v;
    }
}

extern "C" void kernel_launch(void* const* d_in, const int* in_sizes, int n_in,
                              void* d_out, int out_size, void* d_ws, size_t ws_size,
                              hipStream_t stream) {
    // Size-scan input assignment (dict order: qps, kps, qpn, kpn)
    const float *qps = nullptr, *kps = nullptr, *qpn = nullptr, *kpn = nullptr;
    for (int idx = 0; idx < n_in; ++idx) {
        if (in_sizes[idx] == 256 * 32 * 8 * 64) {
            if (!qps) qps = (const float*)d_in[idx];
            else if (!kps) kps = (const float*)d_in[idx];
        } else if (in_sizes[idx] == 256 * 8 * 8 * 64) {
            if (!qpn) qpn = (const float*)d_in[idx];
            else if (!kpn) kpn = (const float*)d_in[idx];
        }
    }

    float* ws_ps = (float*)d_ws;            // 64*8*1024 floats (2 MB)
    float* ws_pn = ws_ps + 64 * 8 * 1024;   // 64*8*64 floats (128 KB)

    // PROBE: each kernel launched twice (idempotent). See header comment.
    scores_kernel<<<1024, 256, 0, stream>>>(qps, kps, qpn, kpn, ws_ps, ws_pn);
    scores_kernel<<<1024, 256, 0, stream>>>(qps, kps, qpn, kpn, ws_ps, ws_pn);
    writer_kernel<<<8192, 256, 0, stream>>>(ws_ps, ws_pn, (float*)d_out);
    writer_kernel<<<8192, 256, 0, stream>>>(ws_ps, ws_pn, (float*)d_out);
}

// Round 4
// 106.111 us; speedup vs baseline: 1.2239x; 1.2239x over previous
//
#include <hip/hip_runtime.h>
#include <stdint.h>

// fp32 inputs, fp32 outputs:
// qps/kps: [256][32][8][64] f32 ; qpn/kpn: [256][8][8][64] f32
// d_out: f32, FIRST s_ps repeat-expanded [8][8][256][256], THEN s_pn tiled.
// S[b,h,l,s] = (1/8)*sum_e Q[b,l,h,e]K[b,s,h,e]; softmax over s; mean over
// the 32 channels (b = bo*32+ch).
//
// R17 probe: OH = 87.3 us harness-fixed (268MB ws re-poison fill = 41 us
// @83% peak); controllable S+W ~= 18-19 us vs ~12.5 us floor. Slack is in
// scores: 69,632 B LDS -> 2 blocks/CU -> stage/LDS latency not hidden.
//
// R18: half-c staged tiles. T[4][2][32*9] f4 = 36,864 B -> 4 blocks/CU
// (16 waves/CU, launch_bounds(256,4)). Per wave: issue ALL 16 global f4
// loads up front -> ds_write h0 -> compute c0..7 -> ds_write h1 (in-wave
// LDS pipe order, no barrier) -> compute c8..15. Stage latency hidden in
// registers across compute-h0. Accumulation order c=0..15 unchanged ->
// bitwise-identical output. Branch B / epilogue / writer = R16 verbatim.

__global__ __launch_bounds__(256, 4)
void scores_kernel(const float* __restrict__ qps,
                   const float* __restrict__ kps,
                   const float* __restrict__ qpn,
                   const float* __restrict__ kpn,
                   float* __restrict__ ws_ps,   // [64][8][1024] chunk partials
                   float* __restrict__ ws_pn)   // [64][8][64]   chunk partials
{
    // per-channel HALF tiles: [ch][0]=Q, [ch][1]=K; 32 rows x 9 float4 (pad)
    __shared__ float4 T[4][2][32 * 9];         // 36,864 B -> 4 blocks/CU
    const int tid  = threadIdx.x;
    const int wv   = tid >> 6;
    const int lane = tid & 63;
    const int blk  = blockIdx.x;

    if (blk < 512) {
        // ---- patch_size: block = (a, chunk); wave wv = channel chunk*4+wv ----
        const int a     = blk >> 3;    // bo*8 + h
        const int chunk = blk & 7;
        const int bo = a >> 3, h = a & 7;
        const int b  = bo * 32 + chunk * 4 + wv;    // this wave's channel

        const float4* Q4 = reinterpret_cast<const float4*>(qps);
        const float4* K4 = reinterpret_cast<const float4*>(kps);

        // lane decomposition shared by stage and compute:
        const int rg = lane >> 3;      // 0..7  (stage: row group; compute: row group)
        const int cg = lane & 7;       // 0..7  (stage: f4 col;   compute: col group)

        // ---- issue ALL global loads up front (8 f4 rows-halves x Q,K) ----
        float4 q0[4], k0[4], q1[4], k1[4];
        #pragma unroll
        for (int i = 0; i < 4; ++i) {
            const int row  = 8 * i + rg;
            const int base = ((b * 32 + row) * 8 + h) * 16;
            q0[i] = Q4[base + cg];
            k0[i] = K4[base + cg];
            q1[i] = Q4[base + 8 + cg];
            k1[i] = K4[base + 8 + cg];
        }

        // ---- stage half 0 (c = 0..7): 8-lane groups write 128 B segments ----
        #pragma unroll
        for (int i = 0; i < 4; ++i) {
            const int row = 8 * i + rg;
            T[wv][0][row * 9 + cg] = q0[i];
            T[wv][1][row * 9 + cg] = k0[i];
        }
        // NO __syncthreads: wave-lockstep LDS visibility (own writes only).

        float acc[4][4];
        #pragma unroll
        for (int r = 0; r < 4; ++r)
            #pragma unroll
            for (int u = 0; u < 4; ++u) acc[r][u] = 0.f;

        // ---- compute half 0: rows rg+8r, cols cg+8u; banks 4(rg+c): free ----
        #pragma unroll
        for (int c = 0; c < 8; ++c) {
            float4 qv[4], kv[4];
            #pragma unroll
            for (int r = 0; r < 4; ++r) qv[r] = T[wv][0][(rg + 8 * r) * 9 + c];
            #pragma unroll
            for (int u = 0; u < 4; ++u) kv[u] = T[wv][1][(cg + 8 * u) * 9 + c];
            #pragma unroll
            for (int r = 0; r < 4; ++r)
                #pragma unroll
                for (int u = 0; u < 4; ++u) {
                    acc[r][u] = fmaf(qv[r].x, kv[u].x, acc[r][u]);
                    acc[r][u] = fmaf(qv[r].y, kv[u].y, acc[r][u]);
                    acc[r][u] = fmaf(qv[r].z, kv[u].z, acc[r][u]);
                    acc[r][u] = fmaf(qv[r].w, kv[u].w, acc[r][u]);
                }
        }

        // ---- stage half 1 over the same LDS (in-order LDS pipe per wave) ----
        #pragma unroll
        for (int i = 0; i < 4; ++i) {
            const int row = 8 * i + rg;
            T[wv][0][row * 9 + cg] = q1[i];
            T[wv][1][row * 9 + cg] = k1[i];
        }

        // ---- compute half 1 (logical c = 8..15, same acc chain order) ----
        #pragma unroll
        for (int c = 0; c < 8; ++c) {
            float4 qv[4], kv[4];
            #pragma unroll
            for (int r = 0; r < 4; ++r) qv[r] = T[wv][0][(rg + 8 * r) * 9 + c];
            #pragma unroll
            for (int u = 0; u < 4; ++u) kv[u] = T[wv][1][(cg + 8 * u) * 9 + c];
            #pragma unroll
            for (int r = 0; r < 4; ++r)
                #pragma unroll
                for (int u = 0; u < 4; ++u) {
                    acc[r][u] = fmaf(qv[r].x, kv[u].x, acc[r][u]);
                    acc[r][u] = fmaf(qv[r].y, kv[u].y, acc[r][u]);
                    acc[r][u] = fmaf(qv[r].z, kv[u].z, acc[r][u]);
                    acc[r][u] = fmaf(qv[r].w, kv[u].w, acc[r][u]);
                }
        }

        // ---- softmax per row; /32 for channel mean ----
        #pragma unroll
        for (int r = 0; r < 4; ++r) {
            float v0 = acc[r][0] * 0.125f, v1 = acc[r][1] * 0.125f;
            float v2 = acc[r][2] * 0.125f, v3 = acc[r][3] * 0.125f;
            float m = fmaxf(fmaxf(v0, v1), fmaxf(v2, v3));
            m = fmaxf(m, __shfl_xor(m, 1));
            m = fmaxf(m, __shfl_xor(m, 2));
            m = fmaxf(m, __shfl_xor(m, 4));
            float e0 = __expf(v0 - m), e1 = __expf(v1 - m);
            float e2 = __expf(v2 - m), e3 = __expf(v3 - m);
            float s = (e0 + e1) + (e2 + e3);
            s += __shfl_xor(s, 1);
            s += __shfl_xor(s, 2);
            s += __shfl_xor(s, 4);
            const float inv = 1.f / (s * 32.f);
            acc[r][0] = e0 * inv; acc[r][1] = e1 * inv;
            acc[r][2] = e2 * inv; acc[r][3] = e3 * inv;
        }

        // ---- cross-wave (4-channel) sum via swizzled LDS ----
        __syncthreads();                 // everyone done with tiles
        float* P = reinterpret_cast<float*>(T);   // [4][1024] floats (16 KB)
        #pragma unroll
        for (int r = 0; r < 4; ++r) {
            const int row = rg + 8 * r;
            const int sw  = (row & 3) << 3;
            #pragma unroll
            for (int u = 0; u < 4; ++u) {
                const int col = cg + 8 * u;
                P[wv * 1024 + row * 32 + (col ^ sw)] = acc[r][u];
            }
        }
        __syncthreads();

        // reduce channels in order wv=0..3; store coalesced f4
        {
            const int row = tid >> 3;
            const int c0  = (tid & 7) * 4;
            const int sw  = (row & 3) << 3;
            float vx[4];
            #pragma unroll
            for (int x = 0; x < 4; ++x) {
                const int ci = row * 32 + ((c0 + x) ^ sw);
                float v = P[ci];
                v += P[1024 + ci];
                v += P[2048 + ci];
                v += P[3072 + ci];
                vx[x] = v;
            }
            float4 o; o.x = vx[0]; o.y = vx[1]; o.z = vx[2]; o.w = vx[3];
            reinterpret_cast<float4*>(ws_ps + (a * 8 + chunk) * 1024)[tid] = o;
        }
    } else {
        // ---- patch_num: block (a2, chunk); wave wv = channel chunk*4+wv ----
        float* red = reinterpret_cast<float*>(T);   // [4][64] reuse
        const int bb    = blk - 512;
        const int a2    = bb >> 3;     // bo*8 + h
        const int chunk = bb & 7;
        const int bo = a2 >> 3, h = a2 & 7;
        const int b  = bo * 32 + chunk * 4 + wv;
        const int i = lane >> 3, j = lane & 7;
        const float4* qv = reinterpret_cast<const float4*>(qpn) + ((b * 8 + i) * 8 + h) * 16;
        const float4* kv = reinterpret_cast<const float4*>(kpn) + ((b * 8 + j) * 8 + h) * 16;

        float acc = 0.f;
        #pragma unroll
        for (int c = 0; c < 16; ++c) {
            float4 q = qv[c], k = kv[c];
            acc = fmaf(q.x, k.x, acc);
            acc = fmaf(q.y, k.y, acc);
            acc = fmaf(q.z, k.z, acc);
            acc = fmaf(q.w, k.w, acc);
        }
        const float s = acc * 0.125f;
        float m = s;
        m = fmaxf(m, __shfl_xor(m, 1));
        m = fmaxf(m, __shfl_xor(m, 2));
        m = fmaxf(m, __shfl_xor(m, 4));
        float e = __expf(s - m);
        float sum = e;
        sum += __shfl_xor(sum, 1);
        sum += __shfl_xor(sum, 2);
        sum += __shfl_xor(sum, 4);

        red[wv * 64 + lane] = e / (sum * 32.f);
        __syncthreads();
        if (tid < 64) {
            ws_pn[(a2 * 8 + chunk) * 64 + tid] =
                (red[0 * 64 + tid] + red[1 * 64 + tid]) +
                (red[2 * 64 + tid] + red[3 * 64 + tid]);
        }
    }
}

// Fused 8-chunk reduce + expansion writer.
__global__ __launch_bounds__(256)
void writer_kernel(const float* __restrict__ ws_ps,
                   const float* __restrict__ ws_pn,
                   float* __restrict__ out)
{
    const int g = blockIdx.x * 256 + threadIdx.x;   // float4 index
    float4* o4 = reinterpret_cast<float4*>(out);
    if (g < 1048576) {
        // out0[a][i][j] = sum_c ws_ps[a][c][(i>>3)*32 + (j>>3)]
        const int a  = g >> 14;
        const int r  = g & 16383;
        const int i  = r >> 6;
        const int j4 = r & 63;
        const float* base = ws_ps + a * 8192 + (i >> 3) * 32 + (j4 >> 1);
        float v = 0.f;
        #pragma unroll
        for (int c = 0; c < 8; ++c) v += base[c * 1024];   // chunk-sequential
        float4 o; o.x = v; o.y = v; o.z = v; o.w = v;
        o4[g] = o;
    } else {
        // out1[a][i][j] = sum_c ws_pn[a][c][(i&7)*8 + (j&7)]
        const int g2 = g - 1048576;
        const int a  = g2 >> 14;
        const int r  = g2 & 16383;
        const int i  = r >> 6;
        const int j4 = r & 63;
        const float4* base = reinterpret_cast<const float4*>(
            ws_pn + a * 512 + (i & 7) * 8 + 4 * (j4 & 1));
        float4 v; v.x = 0.f; v.y = 0.f; v.z = 0.f; v.w = 0.f;
        #pragma unroll
        for (int c = 0; c < 8; ++c) {
            float4 t = base[c * 16];                       // chunk-sequential
            v.x += t.x; v.y += t.y; v.z += t.z; v.w += t.w;
        }
        o4[g] = v;
    }
}

extern "C" void kernel_launch(void* const* d_in, const int* in_sizes, int n_in,
                              void* d_out, int out_size, void* d_ws, size_t ws_size,
                              hipStream_t stream) {
    // Size-scan input assignment (dict order: qps, kps, qpn, kpn)
    const float *qps = nullptr, *kps = nullptr, *qpn = nullptr, *kpn = nullptr;
    for (int idx = 0; idx < n_in; ++idx) {
        if (in_sizes[idx] == 256 * 32 * 8 * 64) {
            if (!qps) qps = (const float*)d_in[idx];
            else if (!kps) kps = (const float*)d_in[idx];
        } else if (in_sizes[idx] == 256 * 8 * 8 * 64) {
            if (!qpn) qpn = (const float*)d_in[idx];
            else if (!kpn) kpn = (const float*)d_in[idx];
        }
    }

    float* ws_ps = (float*)d_ws;            // 64*8*1024 floats (2 MB)
    float* ws_pn = ws_ps + 64 * 8 * 1024;   // 64*8*64 floats (128 KB)

    scores_kernel<<<1024, 256, 0, stream>>>(qps, kps, qpn, kpn, ws_ps, ws_pn);
    writer_kernel<<<8192, 256, 0, stream>>>(ws_ps, ws_pn, (float*)d_out);
}